// Round 1
// baseline (395.899 us; speedup 1.0000x reference)
//
#include <hip/hip_runtime.h>
#include <math.h>

#define B 2048
#define D 512
#define NC 32

// ---------------------------------------------------------------------------
// Workspace layout (all fits in ~330 KB):
//   int   counts[NC]
//   int   lists[NC][B]
//   float centers[NC][D]
//   float partial[NC]
// ---------------------------------------------------------------------------

// Deterministic per-class member lists (no atomics -> identical order every
// replay). One block per class; 256 threads scan strided, then prefix-scan.
__global__ void build_lists_kernel(const int* __restrict__ target,
                                   int* __restrict__ counts,
                                   int* __restrict__ lists) {
    const int c = blockIdx.x;
    const int t = threadIdx.x;
    __shared__ int scnt[256];
    __shared__ int soff[257];

    int local = 0;
    for (int i = t; i < B; i += 256) local += (target[i] == c) ? 1 : 0;
    scnt[t] = local;
    __syncthreads();
    if (t == 0) {
        int acc = 0;
        for (int k = 0; k < 256; ++k) { soff[k] = acc; acc += scnt[k]; }
        soff[256] = acc;
        counts[c] = acc;
    }
    __syncthreads();
    int pos = soff[t];
    for (int i = t; i < B; i += 256) {
        if (target[i] == c) lists[c * B + (pos++)] = i;
    }
}

// One block per class: column-parallel sum over members, divide by max(n,1).
__global__ void centers_kernel(const float* __restrict__ y,
                               const int* __restrict__ counts,
                               const int* __restrict__ lists,
                               float* __restrict__ centers) {
    const int c = blockIdx.x;
    const int t = threadIdx.x;  // 256 threads, each owns dims t and t+256
    __shared__ int slist[B];
    const int n = counts[c];
    for (int m = t; m < n; m += 256) slist[m] = lists[c * B + m];
    __syncthreads();

    float acc0 = 0.f, acc1 = 0.f;
    for (int m = 0; m < n; ++m) {
        const float* row = y + (size_t)slist[m] * D;
        acc0 += row[t];
        acc1 += row[t + 256];
    }
    const float den = fmaxf((float)n, 1.0f);
    centers[c * D + t]       = acc0 / den;
    centers[c * D + t + 256] = acc1 / den;
}

// One block per class: top-2 largest intra-class pairwise distances.
__global__ void top2_kernel(const float* __restrict__ y,
                            const int* __restrict__ counts,
                            const int* __restrict__ lists,
                            float* __restrict__ partial) {
    const int c = blockIdx.x;
    const int t = threadIdx.x;
    __shared__ int slist[B];
    const int n = counts[c];
    for (int m = t; m < n; m += 256) slist[m] = lists[c * B + m];
    __syncthreads();

    float t0 = -INFINITY, t1 = -INFINITY;
    const int nn = n * n;
    for (int p = t; p < nn; p += 256) {
        const int i = p / n;
        const int j = p - i * n;
        if (i >= j) continue;  // upper triangle only (i < j)
        const float4* ya = (const float4*)(y + (size_t)slist[i] * D);
        const float4* yb = (const float4*)(y + (size_t)slist[j] * D);
        float ssd = 0.f;
#pragma unroll 8
        for (int k = 0; k < D / 4; ++k) {
            const float4 u = ya[k];
            const float4 v = yb[k];
            const float d0 = u.x - v.x, d1 = u.y - v.y;
            const float d2 = u.z - v.z, d3 = u.w - v.w;
            ssd += d0 * d0 + d1 * d1 + d2 * d2 + d3 * d3;
        }
        const float dd = sqrtf(ssd);
        if (dd > t0) { t1 = t0; t0 = dd; }
        else if (dd > t1) { t1 = dd; }
    }

    __shared__ float s0[256], s1[256];
    s0[t] = t0; s1[t] = t1;
    __syncthreads();
    if (t == 0) {
        float b0 = -INFINITY, b1 = -INFINITY;
        for (int k = 0; k < 256; ++k) {
            const float a0 = s0[k], a1 = s1[k];
            if (a0 > b0) { b1 = b0; b0 = a0; } else if (a0 > b1) { b1 = a0; }
            if (a1 > b0) { b1 = b0; b0 = a1; } else if (a1 > b1) { b1 = a1; }
        }
        // K / (sum of top-2); if class has <2 pairs this is 2/-inf = -0, which
        // matches the reference's top_k-with--inf behavior.
        partial[c] = 2.0f / (b0 + b1);
    }
}

// Single block: min pairwise center distance + combine partials -> scalar out.
__global__ void final_kernel(const float* __restrict__ centers,
                             const float* __restrict__ partial,
                             float* __restrict__ out) {
    const int t = threadIdx.x;
    float dmin = INFINITY;
    for (int p = t; p < NC * NC; p += 256) {
        const int i = p >> 5;
        const int j = p & 31;
        if (i >= j) continue;
        const float4* ca = (const float4*)(centers + i * D);
        const float4* cb = (const float4*)(centers + j * D);
        float ssd = 0.f;
#pragma unroll 8
        for (int k = 0; k < D / 4; ++k) {
            const float4 u = ca[k];
            const float4 v = cb[k];
            const float d0 = u.x - v.x, d1 = u.y - v.y;
            const float d2 = u.z - v.z, d3 = u.w - v.w;
            ssd += d0 * d0 + d1 * d1 + d2 * d2 + d3 * d3;
        }
        dmin = fminf(dmin, sqrtf(ssd));
    }
    __shared__ float sm[256];
    sm[t] = dmin;
    __syncthreads();
    if (t == 0) {
        float m = INFINITY;
        for (int k = 0; k < 256; ++k) m = fminf(m, sm[k]);
        float li = 0.f;
        for (int c = 0; c < NC; ++c) li += partial[c];
        out[0] = 1.0f * li + 0.5f * fmaxf(10.0f - m, 0.0f);
    }
}

extern "C" void kernel_launch(void* const* d_in, const int* in_sizes, int n_in,
                              void* d_out, int out_size, void* d_ws, size_t ws_size,
                              hipStream_t stream) {
    const float* y      = (const float*)d_in[0];
    const int*   target = (const int*)d_in[1];
    float*       out    = (float*)d_out;

    int*   counts  = (int*)d_ws;
    int*   lists   = counts + NC;
    float* centers = (float*)(lists + NC * B);
    float* partial = centers + NC * D;

    build_lists_kernel<<<NC, 256, 0, stream>>>(target, counts, lists);
    centers_kernel<<<NC, 256, 0, stream>>>(y, counts, lists, centers);
    top2_kernel<<<NC, 256, 0, stream>>>(y, counts, lists, partial);
    final_kernel<<<1, 256, 0, stream>>>(centers, partial, out);
}

// Round 2
// 108.704 us; speedup vs baseline: 3.6420x; 3.6420x over previous
//
#include <hip/hip_runtime.h>
#include <math.h>

#define B 2048
#define D 512
#define NC 32
#define SLICES 64   // pair-space splits per class

// ---------------------------------------------------------------------------
// Workspace layout:
//   int   counts[NC]
//   int   lists[NC][B]
//   float centers[NC][D]
//   float blk_top[NC][SLICES][2]   (per-slice top-2 partials)
// ---------------------------------------------------------------------------

// Deterministic per-class member lists (no atomics -> identical every replay).
__global__ void build_lists_kernel(const int* __restrict__ target,
                                   int* __restrict__ counts,
                                   int* __restrict__ lists) {
    const int c = blockIdx.x;
    const int t = threadIdx.x;
    __shared__ int scnt[256];
    __shared__ int soff[257];

    int local = 0;
    for (int i = t; i < B; i += 256) local += (target[i] == c) ? 1 : 0;
    scnt[t] = local;
    __syncthreads();
    if (t == 0) {
        int acc = 0;
        for (int k = 0; k < 256; ++k) { soff[k] = acc; acc += scnt[k]; }
        counts[c] = acc;
    }
    __syncthreads();
    int pos = soff[t];
    for (int i = t; i < B; i += 256) {
        if (target[i] == c) lists[c * B + (pos++)] = i;
    }
}

// One block per class: column-parallel sum over members, divide by max(n,1).
__global__ void centers_kernel(const float* __restrict__ y,
                               const int* __restrict__ counts,
                               const int* __restrict__ lists,
                               float* __restrict__ centers) {
    const int c = blockIdx.x;
    const int t = threadIdx.x;  // 256 threads, each owns dims t and t+256
    __shared__ int slist[B];
    const int n = counts[c];
    for (int m = t; m < n; m += 256) slist[m] = lists[c * B + m];
    __syncthreads();

    float acc0 = 0.f, acc1 = 0.f;
    for (int m = 0; m < n; ++m) {
        const float* row = y + (size_t)slist[m] * D;
        acc0 += row[t];
        acc1 += row[t + 256];
    }
    const float den = fmaxf((float)n, 1.0f);
    centers[c * D + t]       = acc0 / den;
    centers[c * D + t + 256] = acc1 / den;
}

// One WAVE per pair, 64 lanes split the 512-dim distance (8 floats/lane,
// coalesced 32B/lane row reads). Grid: (SLICES, NC), 4 waves/block.
__global__ void top2_pairs_kernel(const float* __restrict__ y,
                                  const int* __restrict__ counts,
                                  const int* __restrict__ lists,
                                  float* __restrict__ blk_top) {
    const int c = blockIdx.y;
    const int s = blockIdx.x;
    const int t = threadIdx.x;
    const int wave = t >> 6;
    const int lane = t & 63;

    __shared__ int slist[B];
    const int n = counts[c];
    for (int m = t; m < n; m += 256) slist[m] = lists[c * B + m];
    __syncthreads();

    float t0 = -INFINITY, t1 = -INFINITY;
    const int nn = n * n;
    // wave-global pair-slot index, stride over the full n*n grid (i<j kept)
    for (int p = s * 4 + wave; p < nn; p += SLICES * 4) {
        const int i = p / n;
        const int j = p - i * n;
        if (i >= j) continue;
        const float4* ya = (const float4*)(y + (size_t)slist[i] * D) + lane * 2;
        const float4* yb = (const float4*)(y + (size_t)slist[j] * D) + lane * 2;
        const float4 u0 = ya[0], u1 = ya[1];
        const float4 v0 = yb[0], v1 = yb[1];
        float d, ssd = 0.f;
        d = u0.x - v0.x; ssd += d * d;
        d = u0.y - v0.y; ssd += d * d;
        d = u0.z - v0.z; ssd += d * d;
        d = u0.w - v0.w; ssd += d * d;
        d = u1.x - v1.x; ssd += d * d;
        d = u1.y - v1.y; ssd += d * d;
        d = u1.z - v1.z; ssd += d * d;
        d = u1.w - v1.w; ssd += d * d;
        // butterfly reduce across the 64-lane wave -> all lanes hold total
        for (int off = 32; off > 0; off >>= 1) ssd += __shfl_xor(ssd, off, 64);
        const float dd = sqrtf(ssd);
        if (dd > t0) { t1 = t0; t0 = dd; }
        else if (dd > t1) { t1 = dd; }
    }

    __shared__ float s0[4], s1[4];
    if (lane == 0) { s0[wave] = t0; s1[wave] = t1; }
    __syncthreads();
    if (t == 0) {
        float b0 = -INFINITY, b1 = -INFINITY;
        for (int w = 0; w < 4; ++w) {
            const float a0 = s0[w], a1 = s1[w];
            if (a0 > b0) { b1 = b0; b0 = a0; } else if (a0 > b1) { b1 = a0; }
            if (a1 > b0) { b1 = b0; b0 = a1; } else if (a1 > b1) { b1 = a1; }
        }
        blk_top[(c * SLICES + s) * 2]     = b0;
        blk_top[(c * SLICES + s) * 2 + 1] = b1;
    }
}

// Single block: merge per-slice top-2 -> l_intra; min center distance -> out.
__global__ void final_kernel(const float* __restrict__ centers,
                             const float* __restrict__ blk_top,
                             float* __restrict__ out) {
    const int t = threadIdx.x;
    __shared__ float li_sh[NC];
    if (t < NC) {
        float b0 = -INFINITY, b1 = -INFINITY;
        for (int s = 0; s < SLICES; ++s) {
            const float a0 = blk_top[(t * SLICES + s) * 2];
            const float a1 = blk_top[(t * SLICES + s) * 2 + 1];
            if (a0 > b0) { b1 = b0; b0 = a0; } else if (a0 > b1) { b1 = a0; }
            if (a1 > b0) { b1 = b0; b0 = a1; } else if (a1 > b1) { b1 = a1; }
        }
        li_sh[t] = 2.0f / (b0 + b1);
    }
    __syncthreads();

    float dmin = INFINITY;
    for (int p = t; p < NC * NC; p += 256) {
        const int i = p >> 5;
        const int j = p & 31;
        if (i >= j) continue;
        const float4* ca = (const float4*)(centers + i * D);
        const float4* cb = (const float4*)(centers + j * D);
        float ssd = 0.f;
#pragma unroll 8
        for (int k = 0; k < D / 4; ++k) {
            const float4 u = ca[k];
            const float4 v = cb[k];
            const float d0 = u.x - v.x, d1 = u.y - v.y;
            const float d2 = u.z - v.z, d3 = u.w - v.w;
            ssd += d0 * d0 + d1 * d1 + d2 * d2 + d3 * d3;
        }
        dmin = fminf(dmin, sqrtf(ssd));
    }
    __shared__ float sm[256];
    sm[t] = dmin;
    __syncthreads();
    if (t == 0) {
        float m = INFINITY;
        for (int k = 0; k < 256; ++k) m = fminf(m, sm[k]);
        float li = 0.f;
        for (int c = 0; c < NC; ++c) li += li_sh[c];
        out[0] = 1.0f * li + 0.5f * fmaxf(10.0f - m, 0.0f);
    }
}

extern "C" void kernel_launch(void* const* d_in, const int* in_sizes, int n_in,
                              void* d_out, int out_size, void* d_ws, size_t ws_size,
                              hipStream_t stream) {
    const float* y      = (const float*)d_in[0];
    const int*   target = (const int*)d_in[1];
    float*       out    = (float*)d_out;

    int*   counts  = (int*)d_ws;
    int*   lists   = counts + NC;
    float* centers = (float*)(lists + NC * B);
    float* blk_top = centers + NC * D;

    build_lists_kernel<<<NC, 256, 0, stream>>>(target, counts, lists);
    centers_kernel<<<NC, 256, 0, stream>>>(y, counts, lists, centers);
    top2_pairs_kernel<<<dim3(SLICES, NC), 256, 0, stream>>>(y, counts, lists, blk_top);
    final_kernel<<<1, 256, 0, stream>>>(centers, blk_top, out);
}

// Round 3
// 47.968 us; speedup vs baseline: 8.2534x; 2.2662x over previous
//
#include <hip/hip_runtime.h>
#include <math.h>

#define B 2048
#define D 512
#define NC 32
#define SLICES 32        // pair-space splits per class (64 top-2 partials = 1 wave)
#define CMIN_BLOCKS 256  // 1024 center-pair slots / 4 waves per block

// ---------------------------------------------------------------------------
// Workspace layout:
//   int   counts[NC]
//   int   lists[NC][B]
//   float centers[NC][D]
//   float blk_top[NC][SLICES][2]
//   float cmin[CMIN_BLOCKS]
// ---------------------------------------------------------------------------

// Deterministic per-class member lists (no atomics -> identical every replay).
__global__ void build_lists_kernel(const int* __restrict__ target,
                                   int* __restrict__ counts,
                                   int* __restrict__ lists) {
    const int c = blockIdx.x;
    const int t = threadIdx.x;
    __shared__ int scnt[256];
    __shared__ int soff[256];

    int local = 0;
    for (int i = t; i < B; i += 256) local += (target[i] == c) ? 1 : 0;
    scnt[t] = local;
    __syncthreads();
    if (t == 0) {
        int acc = 0;
        for (int k = 0; k < 256; ++k) { soff[k] = acc; acc += scnt[k]; }
        counts[c] = acc;
    }
    __syncthreads();
    int pos = soff[t];
    for (int i = t; i < B; i += 256) {
        if (target[i] == c) lists[c * B + (pos++)] = i;
    }
}

// One block per class, 1024 threads: 2 member-groups x 512 dims, LDS combine.
__global__ void centers_kernel(const float* __restrict__ y,
                               const int* __restrict__ counts,
                               const int* __restrict__ lists,
                               float* __restrict__ centers) {
    const int c = blockIdx.x;
    const int t = threadIdx.x;
    const int g = t >> 9;        // member group 0/1
    const int d = t & 511;       // dim
    __shared__ int slist[B];
    __shared__ float part[512]; // group-0 partials
    const int n = counts[c];
    for (int m = t; m < n; m += 1024) slist[m] = lists[c * B + m];
    __syncthreads();

    float acc = 0.f;
    for (int m = g; m < n; m += 2) acc += y[(size_t)slist[m] * D + d];
    if (g == 0) part[d] = acc;
    __syncthreads();
    if (g == 1) {
        const float den = fmaxf((float)n, 1.0f);
        centers[c * D + d] = (part[d] + acc) / den;
    }
}

// One WAVE per intra-class pair slot; 64 lanes split the 512-dim distance.
__global__ void top2_pairs_kernel(const float* __restrict__ y,
                                  const int* __restrict__ counts,
                                  const int* __restrict__ lists,
                                  float* __restrict__ blk_top) {
    const int c = blockIdx.y;
    const int s = blockIdx.x;
    const int t = threadIdx.x;
    const int wave = t >> 6;
    const int lane = t & 63;

    __shared__ int slist[B];
    const int n = counts[c];
    for (int m = t; m < n; m += 256) slist[m] = lists[c * B + m];
    __syncthreads();

    float t0 = -INFINITY, t1 = -INFINITY;
    const int nn = n * n;
    for (int p = s * 4 + wave; p < nn; p += SLICES * 4) {
        const int i = p / n;
        const int j = p - i * n;
        if (i >= j) continue;
        const float4* ya = (const float4*)(y + (size_t)slist[i] * D) + lane * 2;
        const float4* yb = (const float4*)(y + (size_t)slist[j] * D) + lane * 2;
        const float4 u0 = ya[0], u1 = ya[1];
        const float4 v0 = yb[0], v1 = yb[1];
        float d, ssd = 0.f;
        d = u0.x - v0.x; ssd += d * d;
        d = u0.y - v0.y; ssd += d * d;
        d = u0.z - v0.z; ssd += d * d;
        d = u0.w - v0.w; ssd += d * d;
        d = u1.x - v1.x; ssd += d * d;
        d = u1.y - v1.y; ssd += d * d;
        d = u1.z - v1.z; ssd += d * d;
        d = u1.w - v1.w; ssd += d * d;
        for (int off = 32; off > 0; off >>= 1) ssd += __shfl_xor(ssd, off, 64);
        const float dd = sqrtf(ssd);
        if (dd > t0) { t1 = t0; t0 = dd; }
        else if (dd > t1) { t1 = dd; }
    }

    __shared__ float s0[4], s1[4];
    if (lane == 0) { s0[wave] = t0; s1[wave] = t1; }
    __syncthreads();
    if (t == 0) {
        float b0 = -INFINITY, b1 = -INFINITY;
        for (int w = 0; w < 4; ++w) {
            const float a0 = s0[w], a1 = s1[w];
            if (a0 > b0) { b1 = b0; b0 = a0; } else if (a0 > b1) { b1 = a0; }
            if (a1 > b0) { b1 = b0; b0 = a1; } else if (a1 > b1) { b1 = a1; }
        }
        blk_top[(c * SLICES + s) * 2]     = b0;
        blk_top[(c * SLICES + s) * 2 + 1] = b1;
    }
}

// Wave-per-center-pair: 1024 (i,j) slots over 256 blocks x 4 waves.
// Lanes split D (32B each), butterfly reduce, block-min -> cmin[block].
__global__ void center_min_kernel(const float* __restrict__ centers,
                                  float* __restrict__ cmin) {
    const int t = threadIdx.x;
    const int wave = t >> 6;
    const int lane = t & 63;
    const int slot = blockIdx.x * 4 + wave;
    const int i = slot >> 5;
    const int j = slot & 31;

    float dd = INFINITY;
    if (i < j) {
        const float4* ca = (const float4*)(centers + i * D) + lane * 2;
        const float4* cb = (const float4*)(centers + j * D) + lane * 2;
        const float4 u0 = ca[0], u1 = ca[1];
        const float4 v0 = cb[0], v1 = cb[1];
        float d, ssd = 0.f;
        d = u0.x - v0.x; ssd += d * d;
        d = u0.y - v0.y; ssd += d * d;
        d = u0.z - v0.z; ssd += d * d;
        d = u0.w - v0.w; ssd += d * d;
        d = u1.x - v1.x; ssd += d * d;
        d = u1.y - v1.y; ssd += d * d;
        d = u1.z - v1.z; ssd += d * d;
        d = u1.w - v1.w; ssd += d * d;
        for (int off = 32; off > 0; off >>= 1) ssd += __shfl_xor(ssd, off, 64);
        dd = sqrtf(ssd);
    }
    __shared__ float sm[4];
    if (lane == 0) sm[wave] = dd;
    __syncthreads();
    if (t == 0) {
        float m = INFINITY;
        for (int w = 0; w < 4; ++w) m = fminf(m, sm[w]);
        cmin[blockIdx.x] = m;
    }
}

// 1 block x 1024 threads: wave w merges classes 2w, 2w+1 (64 slice-partials
// map onto 64 lanes, butterfly top-2 merge); 256 threads reduce cmin.
__global__ void final_merge_kernel(const float* __restrict__ blk_top,
                                   const float* __restrict__ cmin,
                                   float* __restrict__ out) {
    const int t = threadIdx.x;
    const int wave = t >> 6;
    const int lane = t & 63;
    __shared__ float li_sh[NC];
    __shared__ float mn_sh[4];

    for (int cc = 0; cc < 2; ++cc) {
        const int c = wave * 2 + cc;
        float t0 = blk_top[c * SLICES * 2 + lane];  // 64 values = 32 (b0,b1)
        float t1 = -INFINITY;
        for (int off = 32; off > 0; off >>= 1) {
            const float o0 = __shfl_xor(t0, off, 64);
            const float o1 = __shfl_xor(t1, off, 64);
            if (o0 > t0) { t1 = fmaxf(t0, o1); t0 = o0; }
            else         { t1 = fmaxf(t1, o0); }
        }
        if (lane == 0) li_sh[c] = 2.0f / (t0 + t1);
    }

    if (t < CMIN_BLOCKS) {
        float v = cmin[t];
        for (int off = 32; off > 0; off >>= 1)
            v = fminf(v, __shfl_xor(v, off, 64));
        if (lane == 0) mn_sh[wave] = v;
    }
    __syncthreads();

    if (t == 0) {
        float m = INFINITY;
        for (int w = 0; w < 4; ++w) m = fminf(m, mn_sh[w]);
        float li = 0.f;
        for (int c = 0; c < NC; ++c) li += li_sh[c];
        out[0] = 1.0f * li + 0.5f * fmaxf(10.0f - m, 0.0f);
    }
}

extern "C" void kernel_launch(void* const* d_in, const int* in_sizes, int n_in,
                              void* d_out, int out_size, void* d_ws, size_t ws_size,
                              hipStream_t stream) {
    const float* y      = (const float*)d_in[0];
    const int*   target = (const int*)d_in[1];
    float*       out    = (float*)d_out;

    int*   counts  = (int*)d_ws;
    int*   lists   = counts + NC;
    float* centers = (float*)(lists + NC * B);
    float* blk_top = centers + NC * D;
    float* cmin    = blk_top + NC * SLICES * 2;

    build_lists_kernel<<<NC, 256, 0, stream>>>(target, counts, lists);
    centers_kernel<<<NC, 1024, 0, stream>>>(y, counts, lists, centers);
    top2_pairs_kernel<<<dim3(SLICES, NC), 256, 0, stream>>>(y, counts, lists, blk_top);
    center_min_kernel<<<CMIN_BLOCKS, 256, 0, stream>>>(centers, cmin);
    final_merge_kernel<<<1, 1024, 0, stream>>>(blk_top, cmin, out);
}